// Round 13
// baseline (1428.968 us; speedup 1.0000x reference)
//
#include <hip/hip_runtime.h>
#include <hip/hip_bf16.h>
#include <math.h>

#define NN 50000
#define EE 200000
#define ET 250000   // EE + NN self loops
#define GG 64
#define LL 6

using short8 = __attribute__((ext_vector_type(8))) short;
using f32x4  = __attribute__((ext_vector_type(4))) float;
typedef unsigned short ushortT;

__device__ __forceinline__ float elu1(float x) { return x > 0.f ? x : expm1f(x); }
__device__ __forceinline__ float gelu_exact(float x) {
    return 0.5f * x * (1.f + erff(x * 0.70710678118654752440f));
}
__device__ __forceinline__ short f2bf(float f) {
    __hip_bfloat16 h = __float2bfloat16(f);
    return *reinterpret_cast<short*>(&h);
}
__device__ __forceinline__ float bf2f(ushortT u) {
    return __uint_as_float(((unsigned)u) << 16);
}

// ---------------- CSR build ----------------
__global__ void count_deg_kernel(const int* __restrict__ ei, int* __restrict__ deg) {
    int e = blockIdx.x * 256 + threadIdx.x;
    if (e >= ET) return;
    int dst = (e < EE) ? ei[EE + e] : (e - EE);
    atomicAdd(&deg[dst], 1);
}

__global__ void scan_kernel(const int* __restrict__ deg, int* __restrict__ row_ptr, int n) {
    __shared__ int s[1024];
    int tid = threadIdx.x;
    const int per = (n + 1023) / 1024;
    int lo = tid * per, hi = min(lo + per, n);
    int sum = 0;
    for (int i = lo; i < hi; i++) sum += deg[i];
    s[tid] = sum;
    __syncthreads();
    for (int off = 1; off < 1024; off <<= 1) {
        int t = (tid >= off) ? s[tid - off] : 0;
        __syncthreads();
        s[tid] += t;
        __syncthreads();
    }
    int run = s[tid] - sum;
    for (int i = lo; i < hi; i++) { row_ptr[i] = run; run += deg[i]; }
    if (tid == 1023) row_ptr[n] = s[1023];
}

__global__ void fill_csr_kernel(const int* __restrict__ ei, const int* __restrict__ row_ptr,
                                int* __restrict__ cursor, int* __restrict__ edge_src) {
    int e = blockIdx.x * 256 + threadIdx.x;
    if (e >= ET) return;
    int src, dst;
    if (e < EE) { src = ei[e]; dst = ei[EE + e]; }
    else        { src = e - EE; dst = e - EE; }
    int pos = atomicAdd(&cursor[dst], 1);
    edge_src[row_ptr[dst] + pos] = src;
}

__global__ void dinv_kernel(const int* __restrict__ row_ptr, float* __restrict__ dinv) {
    int n = blockIdx.x * 256 + threadIdx.x;
    if (n >= NN) return;
    int d = row_ptr[n + 1] - row_ptr[n];
    dinv[n] = (d > 0) ? rsqrtf((float)d) : 0.f;
}

// ---- fold wv into wo: Wvo = wv@wo, bvo = bv@wo + bo (fp32, exact) ----
__global__ void wvwo_kernel(const float* __restrict__ wv, const float* __restrict__ wo,
                            const float* __restrict__ bv, const float* __restrict__ bo,
                            float* __restrict__ Wvo, float* __restrict__ bvo) {
    int l = blockIdx.y;
    const float* Wv = wv + l * 16384;
    const float* Wo = wo + l * 16384;
    int tid = blockIdx.x * 256 + threadIdx.x;
    if (tid < 16384) {
        int r = tid >> 7, c = tid & 127;
        float s = 0.f;
        for (int k = 0; k < 128; k++) s += Wv[r * 128 + k] * Wo[k * 128 + c];
        Wvo[l * 16384 + tid] = s;
    }
    if (blockIdx.x == 0 && threadIdx.x < 128) {
        int c = threadIdx.x;
        float s = bo[l * 128 + c];
        for (int k = 0; k < 128; k++) s += bv[l * 128 + k] * Wo[k * 128 + c];
        bvo[l * 128 + c] = s;
    }
}

// ---- weight prep: fp32 [K,N] (ldb) -> bf16 MFMA B-fragment order ----
__global__ void bprep_kernel(const float* __restrict__ B, short* __restrict__ Bp,
                             int K, int N, int ldb, long srcStride) {
    int layer = blockIdx.y;
    const float* Bsrc = B + srcStride * layer;
    short* Bd = Bp + (size_t)K * N * layer;
    int total = (K >> 5) * (N >> 4) * 64;
    int tid = blockIdx.x * 256 + threadIdx.x;
    if (tid >= total) return;
    int l = tid & 63;
    int rest = tid >> 6;
    int kbc = K >> 5;
    int kb = rest % kbc;
    int c16 = rest / kbc;
    int n = c16 * 16 + (l & 15);
    int kbase = kb * 32 + (l >> 4) * 8;
    short v[8];
#pragma unroll
    for (int j = 0; j < 8; j++) v[j] = f2bf(Bsrc[(size_t)(kbase + j) * ldb + n]);
    *(uint4*)(Bd + (size_t)tid * 8) = *(uint4*)v;
}

__global__ void cast_bf16_kernel(const float* __restrict__ in, short* __restrict__ out, int n4) {
    int i = blockIdx.x * 256 + threadIdx.x;
    if (i >= n4) return;
    float4 v = *(const float4*)(in + (size_t)i * 4);
    short s[4] = { f2bf(v.x), f2bf(v.y), f2bf(v.z), f2bf(v.w) };
    *(uint2*)(out + (size_t)i * 4) = *(uint2*)s;
}

// ---------------- MFMA GEMM, LDS B-staging, XCD swizzle, RT row-tiles -------
// RT=1 for KBC>0 (whole B tile staged once, one barrier).
// RT=2 for KBC==0 (8KB dbuf slices): each staged B fragment feeds RT MFMAs,
// halving the binding ds_read stream (ds_read b128 ~12cyc vs MFMA ~4.8cyc).
// xcd = bx&7 keeps one row band's NSPLIT column tiles on one XCD L2.
// EPI: 0 plain, 1 gelu, 2 asad + store, 3 residual(bf16)+LN in-place (Nc==128)
template <int EPI, bool BIAS, bool OUTBF16>
__device__ __forceinline__ void epi_store(
    int t2, f32x4 (&acc)[8], int M, int Nc, int rowb, int ln,
    const float* __restrict__ bias, void* __restrict__ Cv,
    const float* __restrict__ a_s, const float* __restrict__ a_d,
    float* __restrict__ as_out, float* __restrict__ ad_out, int asH,
    const ushortT* __restrict__ Rres, const float* __restrict__ lng,
    const float* __restrict__ lnb, float* __restrict__ Qout,
    __hip_bfloat16* __restrict__ Qbout) {
    if (EPI == 2) {
        const float* asv = a_s + t2 * 128;
        const float* adv = a_d + t2 * 128;
#pragma unroll
        for (int reg = 0; reg < 4; reg++) {
            float vs = 0.f, vd = 0.f;
#pragma unroll
            for (int ct = 0; ct < 8; ct++) {
                int colL = ct * 16 + ln;
                float av = acc[ct][reg];
                vs += av * asv[colL];
                vd += av * adv[colL];
            }
            vs += __shfl_xor(vs, 1); vs += __shfl_xor(vs, 2);
            vs += __shfl_xor(vs, 4); vs += __shfl_xor(vs, 8);
            vd += __shfl_xor(vd, 1); vd += __shfl_xor(vd, 2);
            vd += __shfl_xor(vd, 4); vd += __shfl_xor(vd, 8);
            int row = rowb + reg;
            if (ln == 0 && row < M) {
                as_out[(size_t)row * asH + t2] = vs;
                ad_out[(size_t)row * asH + t2] = vd;
            }
        }
    }
    if (EPI == 3) {
        float v[8][4];
#pragma unroll
        for (int ct = 0; ct < 8; ct++) {
            int col = ct * 16 + ln;
            float bv_ = bias[col];
#pragma unroll
            for (int reg = 0; reg < 4; reg++) {
                int row = rowb + reg;
                float r = (row < M) ? bf2f(Rres[(size_t)row * 128 + col]) : 0.f;
                v[ct][reg] = acc[ct][reg] + bv_ + r;
            }
        }
#pragma unroll
        for (int reg = 0; reg < 4; reg++) {
            float s = 0.f;
#pragma unroll
            for (int ct = 0; ct < 8; ct++) s += v[ct][reg];
            s += __shfl_xor(s, 1); s += __shfl_xor(s, 2);
            s += __shfl_xor(s, 4); s += __shfl_xor(s, 8);
            float mean = s * (1.f / 128.f);
            float s2 = 0.f;
#pragma unroll
            for (int ct = 0; ct < 8; ct++) { float d = v[ct][reg] - mean; s2 += d * d; }
            s2 += __shfl_xor(s2, 1); s2 += __shfl_xor(s2, 2);
            s2 += __shfl_xor(s2, 4); s2 += __shfl_xor(s2, 8);
            float rstd = rsqrtf(s2 * (1.f / 128.f) + 1e-5f);
            int row = rowb + reg;
            if (row < M) {
#pragma unroll
                for (int ct = 0; ct < 8; ct++) {
                    int col = ct * 16 + ln;
                    float o = (v[ct][reg] - mean) * rstd * lng[col] + lnb[col];
                    Qbout[(size_t)row * 128 + col] = __float2bfloat16(o);
                    if (Qout) Qout[(size_t)row * 128 + col] = o;
                }
            }
        }
    }
    if (EPI == 0 || EPI == 1 || EPI == 2) {
#pragma unroll
        for (int ct = 0; ct < 8; ct++) {
            int col = t2 * 128 + ct * 16 + ln;
            float bv_ = BIAS ? bias[col] : 0.f;
#pragma unroll
            for (int reg = 0; reg < 4; reg++) {
                int row = rowb + reg;
                if (row < M) {
                    float v = acc[ct][reg] + bv_;
                    if (EPI == 1) v = gelu_exact(v);
                    if (OUTBF16)
                        ((__hip_bfloat16*)Cv)[(size_t)row * Nc + col] = __float2bfloat16(v);
                    else
                        ((float*)Cv)[(size_t)row * Nc + col] = v;
                }
            }
        }
    }
}

template <int EPI, bool BIAS, bool OUTBF16, int NSPLIT, int KBC, int RT>
__global__ __launch_bounds__(256) void gemm_bf16_kernel(
    const short* __restrict__ A, const short* __restrict__ Bp,
    const float* __restrict__ bias, void* __restrict__ Cv,
    const float* __restrict__ a_s, const float* __restrict__ a_d,
    float* __restrict__ as_out, float* __restrict__ ad_out, int asH,
    const ushortT* __restrict__ Rres, const float* __restrict__ lng,
    const float* __restrict__ lnb, float* __restrict__ Qout,
    __hip_bfloat16* __restrict__ Qbout,
    int M, int K, int Nc) {
    __shared__ short Bs[(KBC > 0) ? KBC * 4096 : 8192];
    int t = threadIdx.x;
    int w = t >> 6, l = t & 63;
    int ln = l & 15, lq = l >> 4;
    const int ROWS = 64 * RT;
    int MBceil = (M + ROWS - 1) / ROWS;
    int bx = blockIdx.x;
    int xcd = bx & 7, idx = bx >> 3;
    int t2 = idx % NSPLIT;
    int mb = (idx / NSPLIT) * 8 + xcd;
    if (mb >= MBceil) return;
    int wbase = mb * ROWS + w * 16;

    bool aok[RT];
    const short* Ap[RT];
#pragma unroll
    for (int rt = 0; rt < RT; rt++) {
        int r = wbase + rt * 64 + ln;
        aok[rt] = r < M;
        Ap[rt] = A + (size_t)r * K + lq * 8;
    }

    f32x4 acc[RT][8];
#pragma unroll
    for (int rt = 0; rt < RT; rt++)
#pragma unroll
        for (int j = 0; j < 8; j++) acc[rt][j] = (f32x4){0.f, 0.f, 0.f, 0.f};

    if constexpr (KBC > 0) {
        {
            const uint4* src = (const uint4*)(Bp + (size_t)t2 * KBC * 4096);
            uint4* dst = (uint4*)Bs;
#pragma unroll
            for (int i = 0; i < KBC * 2; i++)
                dst[i * 256 + t] = src[i * 256 + t];
        }
        short8 af[RT][KBC];
#pragma unroll
        for (int rt = 0; rt < RT; rt++)
#pragma unroll
            for (int kb = 0; kb < KBC; kb++)
                af[rt][kb] = aok[rt] ? *(const short8*)(Ap[rt] + kb * 32)
                                     : (short8){0,0,0,0,0,0,0,0};
        __syncthreads();
#pragma unroll
        for (int kb = 0; kb < KBC; kb++)
#pragma unroll
            for (int ct = 0; ct < 8; ct++) {
                short8 bfr = *(const short8*)(Bs + ((ct * KBC + kb) * 64 + l) * 8);
#pragma unroll
                for (int rt = 0; rt < RT; rt++)
                    acc[rt][ct] = __builtin_amdgcn_mfma_f32_16x16x32_bf16(af[rt][kb], bfr, acc[rt][ct], 0, 0, 0);
            }
    } else {
        int kbc = K >> 5;
        int sct = t >> 5, spart = t & 31;
        auto stage = [&](int buf, int kb) {
            const uint4* src = (const uint4*)(Bp + ((size_t)(t2 * 8 + sct) * kbc + kb) * 512);
            uint4* dst = (uint4*)(Bs + buf * 4096 + sct * 512);
            dst[spart * 2]     = src[spart * 2];
            dst[spart * 2 + 1] = src[spart * 2 + 1];
        };
        stage(0, 0);
        __syncthreads();
        for (int kb = 0; kb < kbc; kb++) {
            if (kb + 1 < kbc) stage((kb + 1) & 1, kb + 1);
            short8 af[RT];
#pragma unroll
            for (int rt = 0; rt < RT; rt++)
                af[rt] = aok[rt] ? *(const short8*)(Ap[rt] + kb * 32)
                                 : (short8){0,0,0,0,0,0,0,0};
            const short* bsb = Bs + (kb & 1) * 4096;
#pragma unroll
            for (int ct = 0; ct < 8; ct++) {
                short8 bfr = *(const short8*)(bsb + (ct * 64 + l) * 8);
#pragma unroll
                for (int rt = 0; rt < RT; rt++)
                    acc[rt][ct] = __builtin_amdgcn_mfma_f32_16x16x32_bf16(af[rt], bfr, acc[rt][ct], 0, 0, 0);
            }
            __syncthreads();
        }
    }

#pragma unroll
    for (int rt = 0; rt < RT; rt++) {
        int rowb = wbase + rt * 64 + lq * 4;
        epi_store<EPI, BIAS, OUTBF16>(t2, acc[rt], M, Nc, rowb, ln, bias, Cv,
            a_s, a_d, as_out, ad_out, asH, Rres, lng, lnb, Qout, Qbout);
    }
}

// ---- GAT softmax precompute: one thread per (node, head) -------------------
// Writes unnormalized alpha[e][h] = exp(e-m) and Sinv[n][h] = 1/(S+eps).
template <int H>
__global__ __launch_bounds__(256) void alpha_kernel(
    const float* __restrict__ as_, const float* __restrict__ ad_,
    const int* __restrict__ row_ptr, const int* __restrict__ edge_src,
    float* __restrict__ alpha, float* __restrict__ Sinv, int n_nodes) {
    int idx = blockIdx.x * 256 + threadIdx.x;
    if (idx >= n_nodes * H) return;
    int n = idx / H, h = idx % H;
    int start = row_ptr[n], deg = row_ptr[n + 1] - start;
    float adn = ad_[(size_t)n * H + h];
    float m = -1e30f;
    for (int j = 0; j < deg; j++) {
        int s = edge_src[start + j];
        float e = as_[(size_t)s * H + h] + adn;
        e = e > 0.f ? e : 0.2f * e;
        m = fmaxf(m, e);
    }
    float S = 0.f;
    for (int j = 0; j < deg; j++) {
        int s = edge_src[start + j];
        float e = as_[(size_t)s * H + h] + adn;
        e = e > 0.f ? e : 0.2f * e;
        float wv = expf(e - m);
        S += wv;
        alpha[(size_t)(start + j) * H + h] = wv;
    }
    Sinv[(size_t)n * H + h] = 1.f / (S + 1e-16f);
}

// ---- GAT aggregate: pure weighted gather, 2 nodes/block, 128 thr/node ------
template <int H>
__global__ __launch_bounds__(256) void gat_agg_fused_kernel(
    const ushortT* __restrict__ hpre, const float* __restrict__ alpha,
    const float* __restrict__ Sinv, const float* __restrict__ bias,
    const int* __restrict__ row_ptr, const int* __restrict__ edge_src,
    __hip_bfloat16* __restrict__ out, int n_nodes) {
    const int CPT = H;
    int node = blockIdx.x * 2 + (threadIdx.x >> 7);
    if (node >= n_nodes) return;
    int tt = threadIdx.x & 127;
    int c0 = tt * CPT;
    int hb = c0 >> 7;
    int start = row_ptr[node];
    int deg = row_ptr[node + 1] - start;
    float inv = Sinv[(size_t)node * H + hb];
    float acc[CPT];
#pragma unroll
    for (int c = 0; c < CPT; c++) acc[c] = 0.f;
    for (int j = 0; j < deg; j++) {
        int s = edge_src[start + j];
        float wv = alpha[(size_t)(start + j) * H + hb];
        const ushortT* hp = hpre + (size_t)s * (H * 128) + c0;
        float hv[CPT];
        if (CPT == 8) {
            uint4 u = *(const uint4*)hp;
            hv[0] = bf2f((ushortT)(u.x & 0xffff)); hv[1] = bf2f((ushortT)(u.x >> 16));
            hv[2] = bf2f((ushortT)(u.y & 0xffff)); hv[3] = bf2f((ushortT)(u.y >> 16));
            hv[4] = bf2f((ushortT)(u.z & 0xffff)); hv[5] = bf2f((ushortT)(u.z >> 16));
            hv[6] = bf2f((ushortT)(u.w & 0xffff)); hv[7] = bf2f((ushortT)(u.w >> 16));
        } else {
            uint2 u = *(const uint2*)hp;
            hv[0] = bf2f((ushortT)(u.x & 0xffff)); hv[1] = bf2f((ushortT)(u.x >> 16));
            hv[2] = bf2f((ushortT)(u.y & 0xffff)); hv[3] = bf2f((ushortT)(u.y >> 16));
        }
#pragma unroll
        for (int c = 0; c < CPT; c++) acc[c] += wv * hv[c];
    }
#pragma unroll
    for (int c = 0; c < CPT; c++)
        out[(size_t)node * (H * 128) + c0 + c] =
            __float2bfloat16(elu1(acc[c] * inv + bias[c0 + c]));
}

// ---------------- GCN aggregation (bf16 in) -> bf16 Qb only -----------------
__global__ __launch_bounds__(256) void gcn_agg_kernel(
    const ushortT* __restrict__ hp, const float* __restrict__ dinv,
    const float* __restrict__ b3, const int* __restrict__ row_ptr,
    const int* __restrict__ edge_src,
    __hip_bfloat16* __restrict__ outb, int n_nodes) {
    int node = blockIdx.x * 2 + (threadIdx.x >> 7);
    int c = threadIdx.x & 127;
    if (node >= n_nodes) return;
    int start = row_ptr[node];
    int deg = row_ptr[node + 1] - start;
    float dn = dinv[node];
    float acc = 0.f;
    for (int j = 0; j < deg; j++) {
        int s = edge_src[start + j];
        acc += dinv[s] * dn * bf2f(hp[(size_t)s * 128 + c]);
    }
    outb[(size_t)node * 128 + c] = __float2bfloat16(elu1(acc + b3[c]));
}

// ---------------- pooling ----------------
__global__ void pool1_kernel(const float* __restrict__ Q, const int* __restrict__ batch,
                             float* __restrict__ psum, float* __restrict__ pmax, int n_nodes) {
    int g = blockIdx.x, seg = blockIdx.y;
    int c = threadIdx.x;
    int lo, hi;
    {
        int l = 0, h = n_nodes;
        while (l < h) { int mid = (l + h) >> 1; if (batch[mid] < g) l = mid + 1; else h = mid; }
        lo = l;
        l = lo; h = n_nodes;
        while (l < h) { int mid = (l + h) >> 1; if (batch[mid] < g + 1) l = mid + 1; else h = mid; }
        hi = l;
    }
    int len = hi - lo;
    int a = lo + (int)((long)len * seg / 8);
    int b = lo + (int)((long)len * (seg + 1) / 8);
    float s = 0.f, mx = -INFINITY;
    for (int n = a; n < b; n++) {
        float v = Q[(size_t)n * 128 + c];
        s += v;
        mx = fmaxf(mx, v);
    }
    psum[(g * 8 + seg) * 128 + c] = s;
    pmax[(g * 8 + seg) * 128 + c] = mx;
}

__global__ void pool2_kernel(const float* __restrict__ psum, const float* __restrict__ pmax,
                             const int* __restrict__ batch,
                             const float* __restrict__ bn1g, const float* __restrict__ bn1b,
                             float* __restrict__ hc, int n_nodes) {
    int g = blockIdx.x;
    int c = threadIdx.x;
    int lo, hi;
    {
        int l = 0, h = n_nodes;
        while (l < h) { int mid = (l + h) >> 1; if (batch[mid] < g) l = mid + 1; else h = mid; }
        lo = l;
        l = lo; h = n_nodes;
        while (l < h) { int mid = (l + h) >> 1; if (batch[mid] < g + 1) l = mid + 1; else h = mid; }
        hi = l;
    }
    int cnt = hi - lo;
    float s = 0.f, mx = -INFINITY;
    for (int seg = 0; seg < 8; seg++) {
        s += psum[(g * 8 + seg) * 128 + c];
        mx = fmaxf(mx, pmax[(g * 8 + seg) * 128 + c]);
    }
    float hm = s / fmaxf((float)cnt, 1.f);
    float hx = (cnt > 0 && isfinite(mx)) ? mx : 0.f;
    const float bn_s = 0.99999500003749968f;
    hc[g * 256 + c]       = hm * bn_s * bn1g[c] + bn1b[c];
    hc[g * 256 + 128 + c] = hx * bn_s * bn1g[128 + c] + bn1b[128 + c];
}

__global__ void head_kernel(const float* __restrict__ hc,
                            const float* __restrict__ fc1w, const float* __restrict__ fc1b,
                            const float* __restrict__ bn2g, const float* __restrict__ bn2b,
                            const float* __restrict__ fc2w, const float* __restrict__ fc2b,
                            float* __restrict__ out) {
    int g = blockIdx.x;
    int j = threadIdx.x;
    const float bn_s = 0.99999500003749968f;
    float acc = fc1b[j];
    for (int i = 0; i < 256; i++) acc += hc[g * 256 + i] * fc1w[i * 64 + j];
    acc = elu1(acc);
    acc = acc * bn_s * bn2g[j] + bn2b[j];
    __shared__ float sv[64];
    sv[j] = acc;
    __syncthreads();
    if (j < 2) {
        float o = fc2b[j];
        for (int i = 0; i < 64; i++) o += sv[i] * fc2w[i * 2 + j];
        out[g * 2 + j] = o;
    }
}

// ---------------- launch ----------------
extern "C" void kernel_launch(void* const* d_in, const int* in_sizes, int n_in,
                              void* d_out, int out_size, void* d_ws, size_t ws_size,
                              hipStream_t stream) {
    const float* x    = (const float*)d_in[0];
    const int*   ei   = (const int*)d_in[1];
    const int*   batch= (const int*)d_in[2];
    const float* W1   = (const float*)d_in[3];
    const float* as1  = (const float*)d_in[4];
    const float* ad1  = (const float*)d_in[5];
    const float* b1   = (const float*)d_in[6];
    const float* W2   = (const float*)d_in[7];
    const float* as2  = (const float*)d_in[8];
    const float* ad2  = (const float*)d_in[9];
    const float* b2   = (const float*)d_in[10];
    const float* W3   = (const float*)d_in[11];
    const float* b3   = (const float*)d_in[12];
    const float* wv   = (const float*)d_in[17];
    const float* bv   = (const float*)d_in[18];
    const float* wo   = (const float*)d_in[19];
    const float* bo   = (const float*)d_in[20];
    const float* ln1g = (const float*)d_in[21];
    const float* ln1b = (const float*)d_in[22];
    const float* ln2g = (const float*)d_in[23];
    const float* ln2b = (const float*)d_in[24];
    const float* wf1  = (const float*)d_in[25];
    const float* bf1  = (const float*)d_in[26];
    const float* wf2  = (const float*)d_in[27];
    const float* bf2  = (const float*)d_in[28];
    const float* bn1g = (const float*)d_in[29];
    const float* bn1b = (const float*)d_in[30];
    const float* fc1w = (const float*)d_in[31];
    const float* fc1b = (const float*)d_in[32];
    const float* bn2g = (const float*)d_in[33];
    const float* bn2b = (const float*)d_in[34];
    const float* fc2w = (const float*)d_in[35];
    const float* fc2b = (const float*)d_in[36];
    float* out = (float*)d_out;

    // ---- workspace layout (bytes), peak ~227 MB ----
    // Region A (0..12.8MB): xb during GAT1 gemm; alpha/Sinv afterwards (xb dead).
    char* wsb = (char*)d_ws;
    short* xb    = (short*)wsb;                        // [N,128] bf16 (GAT1 gemm A)
    float* alpha = (float*)wsb;                        // [ET,H] fp32 (GAT agg phase)
    float* Sinv  = (float*)(wsb + 8000000);            // [N,8] fp32
    short* h1pre = (short*)(wsb + 12800000);           // [N,1024] bf16
    short* h2pre = (short*)(wsb + 12800000);           // [N,512] (h1pre dead)
    short* h3pre = (short*)(wsb + 12800000);           // [N,128] (h2pre dead)
    short* FFb   = (short*)(wsb + 25600000);           // [N,512] bf16 (transformer)
    short* bh1   = (short*)(wsb + 115200000);          // [N,1024] bf16
    short* bh2   = (short*)(wsb + 115200000);          // [N,512] (bh1 dead)
    float* fQ    = (float*)(wsb + 128000000);          // [N,128] fp32 (final state only)
    short* Qb    = (short*)(wsb + 153600000);          // [N,128] bf16 transformer state
    char* tail = wsb + 217600000;
    short* W1p  = (short*)tail;  tail += 262144;       // 128x1024
    short* W2p  = (short*)tail;  tail += 1048576;      // 1024x512
    short* W3p  = (short*)tail;  tail += 131072;       // 512x128
    short* Wvop = (short*)tail;  tail += 196608;       // 6 x 128x128
    short* wf1p = (short*)tail;  tail += 786432;       // 6 x 128x512
    short* wf2p = (short*)tail;  tail += 786432;       // 6 x 512x128
    float* Wvo  = (float*)tail;  tail += 393216;       // 6 x 128x128 fp32
    float* bvo  = (float*)tail;  tail += 3072;         // 6 x 128 fp32
    float* fAS  = (float*)tail;  tail += 1600000;      // [N,8]
    float* fAD  = (float*)tail;  tail += 1600000;      // [N,8]
    float* fDv  = (float*)tail;  tail += 200000;
    float* psum = (float*)tail;  tail += 262144;
    float* pmax = (float*)tail;  tail += 262144;
    float* fHC  = (float*)tail;  tail += 65536;
    int* iDeg   = (int*)tail;    tail += 200000;
    int* iRP    = (int*)tail;    tail += 200004;
    int* iCur   = (int*)tail;    tail += 200000;
    int* iES    = (int*)tail;    tail += 1000000;

    hipMemsetAsync(iDeg, 0, NN * sizeof(int), stream);
    hipMemsetAsync(iCur, 0, NN * sizeof(int), stream);

    count_deg_kernel<<<(ET + 255) / 256, 256, 0, stream>>>(ei, iDeg);
    scan_kernel<<<1, 1024, 0, stream>>>(iDeg, iRP, NN);
    fill_csr_kernel<<<(ET + 255) / 256, 256, 0, stream>>>(ei, iRP, iCur, iES);
    dinv_kernel<<<(NN + 255) / 256, 256, 0, stream>>>(iRP, fDv);

    wvwo_kernel<<<dim3(64, 6), 256, 0, stream>>>(wv, wo, bv, bo, Wvo, bvo);
    auto bprep = [&](const float* B, short* Bp, int K, int N, int ldb, long sStride, int layers) {
        int total = (K >> 5) * (N >> 4) * 64;
        dim3 grid((total + 255) / 256, layers);
        bprep_kernel<<<grid, 256, 0, stream>>>(B, Bp, K, N, ldb, sStride);
    };
    bprep(W1, W1p, 128, 1024, 1024, 0, 1);
    bprep(W2, W2p, 1024, 512, 512, 0, 1);
    bprep(W3, W3p, 512, 128, 128, 0, 1);
    bprep(Wvo, Wvop, 128, 128, 128, 16384, 6);
    bprep(wf1, wf1p, 128, 512, 512, 65536, 6);
    bprep(wf2, wf2p, 512, 128, 128, 65536, 6);
    cast_bf16_kernel<<<(NN * 128 / 4 + 255) / 256, 256, 0, stream>>>(x, xb, NN * 128 / 4);

    const int MB64p  = (((NN + 63) / 64 + 7) / 8) * 8;     // 784  (RT=1 blocks)
    const int MB128p = (((NN + 127) / 128 + 7) / 8) * 8;   // 392  (RT=2 blocks)

    // ---- GAT layer 1 (K=128, 8 column tiles, LDS-B, RT=1) ----
    gemm_bf16_kernel<2, false, true, 8, 4, 1><<<MB64p * 8, 256, 0, stream>>>(
        xb, W1p, nullptr, h1pre, as1, ad1, fAS, fAD, 8,
        nullptr, nullptr, nullptr, nullptr, nullptr, NN, 128, 1024);
    // xb dead from here; alpha/Sinv reuse its region
    alpha_kernel<8><<<(NN * 8 + 255) / 256, 256, 0, stream>>>(
        fAS, fAD, iRP, iES, alpha, Sinv, NN);
    gat_agg_fused_kernel<8><<<(NN + 1) / 2, 256, 0, stream>>>(
        (const ushortT*)h1pre, alpha, Sinv, b1, iRP, iES, (__hip_bfloat16*)bh1, NN);
    // ---- GAT layer 2 (K=1024, 4 column tiles, LDS-B dbuf, RT=2) ----
    gemm_bf16_kernel<2, false, true, 4, 0, 2><<<MB128p * 4, 256, 0, stream>>>(
        bh1, W2p, nullptr, h2pre, as2, ad2, fAS, fAD, 4,
        nullptr, nullptr, nullptr, nullptr, nullptr, NN, 1024, 512);
    alpha_kernel<4><<<(NN * 4 + 255) / 256, 256, 0, stream>>>(
        fAS, fAD, iRP, iES, alpha, Sinv, NN);
    gat_agg_fused_kernel<4><<<(NN + 1) / 2, 256, 0, stream>>>(
        (const ushortT*)h2pre, alpha, Sinv, b2, iRP, iES, (__hip_bfloat16*)bh2, NN);
    // ---- GCN (RT=2) ----
    gemm_bf16_kernel<0, false, true, 1, 0, 2><<<MB128p, 256, 0, stream>>>(
        bh2, W3p, nullptr, h3pre, nullptr, nullptr, nullptr, nullptr, 0,
        nullptr, nullptr, nullptr, nullptr, nullptr, NN, 512, 128);
    gcn_agg_kernel<<<(NN + 1) / 2, 256, 0, stream>>>(
        (const ushortT*)h3pre, fDv, b3, iRP, iES, (__hip_bfloat16*)Qb, NN);
    // ---- Transformer (seq_len=1; attn folded; bf16 residual state in Qb) ----
    for (int l = 0; l < LL; l++) {
        gemm_bf16_kernel<3, true, false, 1, 4, 1><<<MB64p, 256, 0, stream>>>(
            Qb, Wvop + l * 16384, bvo + l * 128, nullptr, nullptr, nullptr, nullptr, nullptr, 0,
            (const ushortT*)Qb, ln1g + l * 128, ln1b + l * 128, nullptr, (__hip_bfloat16*)Qb,
            NN, 128, 128);
        gemm_bf16_kernel<1, true, true, 4, 4, 1><<<MB64p * 4, 256, 0, stream>>>(
            Qb, wf1p + l * 65536, bf1 + l * 512, FFb, nullptr, nullptr, nullptr, nullptr, 0,
            nullptr, nullptr, nullptr, nullptr, nullptr, NN, 128, 512);
        gemm_bf16_kernel<3, true, false, 1, 0, 2><<<MB128p, 256, 0, stream>>>(
            FFb, wf2p + l * 65536, bf2 + l * 128, nullptr, nullptr, nullptr, nullptr, nullptr, 0,
            (const ushortT*)Qb, ln2g + l * 128, ln2b + l * 128,
            (l == LL - 1) ? fQ : nullptr, (__hip_bfloat16*)Qb, NN, 512, 128);
    }
    // ---- pool + head ----
    pool1_kernel<<<dim3(GG, 8), 128, 0, stream>>>(fQ, batch, psum, pmax, NN);
    pool2_kernel<<<GG, 128, 0, stream>>>(psum, pmax, batch, bn1g, bn1b, fHC, NN);
    head_kernel<<<GG, 64, 0, stream>>>(fHC, fc1w, fc1b, bn2g, bn2b, fc2w, fc2b, out);
}

// Round 14
// 1411.140 us; speedup vs baseline: 1.0126x; 1.0126x over previous
//
#include <hip/hip_runtime.h>
#include <hip/hip_bf16.h>
#include <math.h>

#define NN 50000
#define EE 200000
#define ET 250000   // EE + NN self loops
#define GG 64
#define LL 6

using short8 = __attribute__((ext_vector_type(8))) short;
using f32x4  = __attribute__((ext_vector_type(4))) float;
typedef unsigned short ushortT;

__device__ __forceinline__ float elu1(float x) { return x > 0.f ? x : expm1f(x); }
__device__ __forceinline__ float gelu_exact(float x) {
    return 0.5f * x * (1.f + erff(x * 0.70710678118654752440f));
}
__device__ __forceinline__ short f2bf(float f) {
    __hip_bfloat16 h = __float2bfloat16(f);
    return *reinterpret_cast<short*>(&h);
}
__device__ __forceinline__ float bf2f(ushortT u) {
    return __uint_as_float(((unsigned)u) << 16);
}

// ---------------- CSR build ----------------
__global__ void count_deg_kernel(const int* __restrict__ ei, int* __restrict__ deg) {
    int e = blockIdx.x * 256 + threadIdx.x;
    if (e >= ET) return;
    int dst = (e < EE) ? ei[EE + e] : (e - EE);
    atomicAdd(&deg[dst], 1);
}

__global__ void scan_kernel(const int* __restrict__ deg, int* __restrict__ row_ptr, int n) {
    __shared__ int s[1024];
    int tid = threadIdx.x;
    const int per = (n + 1023) / 1024;
    int lo = tid * per, hi = min(lo + per, n);
    int sum = 0;
    for (int i = lo; i < hi; i++) sum += deg[i];
    s[tid] = sum;
    __syncthreads();
    for (int off = 1; off < 1024; off <<= 1) {
        int t = (tid >= off) ? s[tid - off] : 0;
        __syncthreads();
        s[tid] += t;
        __syncthreads();
    }
    int run = s[tid] - sum;
    for (int i = lo; i < hi; i++) { row_ptr[i] = run; run += deg[i]; }
    if (tid == 1023) row_ptr[n] = s[1023];
}

__global__ void fill_csr_kernel(const int* __restrict__ ei, const int* __restrict__ row_ptr,
                                int* __restrict__ cursor, int* __restrict__ edge_src) {
    int e = blockIdx.x * 256 + threadIdx.x;
    if (e >= ET) return;
    int src, dst;
    if (e < EE) { src = ei[e]; dst = ei[EE + e]; }
    else        { src = e - EE; dst = e - EE; }
    int pos = atomicAdd(&cursor[dst], 1);
    edge_src[row_ptr[dst] + pos] = src;
}

__global__ void dinv_kernel(const int* __restrict__ row_ptr, float* __restrict__ dinv) {
    int n = blockIdx.x * 256 + threadIdx.x;
    if (n >= NN) return;
    int d = row_ptr[n + 1] - row_ptr[n];
    dinv[n] = (d > 0) ? rsqrtf((float)d) : 0.f;
}

// ---- fold wv into wo: Wvo = wv@wo, bvo = bv@wo + bo (fp32, exact) ----
__global__ void wvwo_kernel(const float* __restrict__ wv, const float* __restrict__ wo,
                            const float* __restrict__ bv, const float* __restrict__ bo,
                            float* __restrict__ Wvo, float* __restrict__ bvo) {
    int l = blockIdx.y;
    const float* Wv = wv + l * 16384;
    const float* Wo = wo + l * 16384;
    int tid = blockIdx.x * 256 + threadIdx.x;
    if (tid < 16384) {
        int r = tid >> 7, c = tid & 127;
        float s = 0.f;
        for (int k = 0; k < 128; k++) s += Wv[r * 128 + k] * Wo[k * 128 + c];
        Wvo[l * 16384 + tid] = s;
    }
    if (blockIdx.x == 0 && threadIdx.x < 128) {
        int c = threadIdx.x;
        float s = bo[l * 128 + c];
        for (int k = 0; k < 128; k++) s += bv[l * 128 + k] * Wo[k * 128 + c];
        bvo[l * 128 + c] = s;
    }
}

// ---- weight prep: fp32 [K,N] (ldb) -> bf16 MFMA B-fragment order ----
__global__ void bprep_kernel(const float* __restrict__ B, short* __restrict__ Bp,
                             int K, int N, int ldb, long srcStride) {
    int layer = blockIdx.y;
    const float* Bsrc = B + srcStride * layer;
    short* Bd = Bp + (size_t)K * N * layer;
    int total = (K >> 5) * (N >> 4) * 64;
    int tid = blockIdx.x * 256 + threadIdx.x;
    if (tid >= total) return;
    int l = tid & 63;
    int rest = tid >> 6;
    int kbc = K >> 5;
    int kb = rest % kbc;
    int c16 = rest / kbc;
    int n = c16 * 16 + (l & 15);
    int kbase = kb * 32 + (l >> 4) * 8;
    short v[8];
#pragma unroll
    for (int j = 0; j < 8; j++) v[j] = f2bf(Bsrc[(size_t)(kbase + j) * ldb + n]);
    *(uint4*)(Bd + (size_t)tid * 8) = *(uint4*)v;
}

__global__ void cast_bf16_kernel(const float* __restrict__ in, short* __restrict__ out, int n4) {
    int i = blockIdx.x * 256 + threadIdx.x;
    if (i >= n4) return;
    float4 v = *(const float4*)(in + (size_t)i * 4);
    short s[4] = { f2bf(v.x), f2bf(v.y), f2bf(v.z), f2bf(v.w) };
    *(uint2*)(out + (size_t)i * 4) = *(uint2*)s;
}

// ---------------- MFMA GEMM, LDS B-staging, XCD swizzle, RT row-tiles -------
// RT=1 for KBC>0 (whole B tile staged once, one barrier).
// RT=2 for KBC==0 (8KB dbuf slices): each staged B fragment feeds RT MFMAs,
// halving the binding ds_read stream (ds_read b128 ~12cyc vs MFMA ~4.8cyc).
// xcd = bx&7 keeps one row band's NSPLIT column tiles on one XCD L2.
// EPI: 0 plain, 1 gelu, 2 asad + store, 3 residual(bf16)+LN in-place (Nc==128)
template <int EPI, bool BIAS, bool OUTBF16>
__device__ __forceinline__ void epi_store(
    int t2, f32x4 (&acc)[8], int M, int Nc, int rowb, int ln,
    const float* __restrict__ bias, void* __restrict__ Cv,
    const float* __restrict__ a_s, const float* __restrict__ a_d,
    float* __restrict__ as_out, float* __restrict__ ad_out, int asH,
    const ushortT* __restrict__ Rres, const float* __restrict__ lng,
    const float* __restrict__ lnb, float* __restrict__ Qout,
    __hip_bfloat16* __restrict__ Qbout) {
    if (EPI == 2) {
        const float* asv = a_s + t2 * 128;
        const float* adv = a_d + t2 * 128;
#pragma unroll
        for (int reg = 0; reg < 4; reg++) {
            float vs = 0.f, vd = 0.f;
#pragma unroll
            for (int ct = 0; ct < 8; ct++) {
                int colL = ct * 16 + ln;
                float av = acc[ct][reg];
                vs += av * asv[colL];
                vd += av * adv[colL];
            }
            vs += __shfl_xor(vs, 1); vs += __shfl_xor(vs, 2);
            vs += __shfl_xor(vs, 4); vs += __shfl_xor(vs, 8);
            vd += __shfl_xor(vd, 1); vd += __shfl_xor(vd, 2);
            vd += __shfl_xor(vd, 4); vd += __shfl_xor(vd, 8);
            int row = rowb + reg;
            if (ln == 0 && row < M) {
                as_out[(size_t)row * asH + t2] = vs;
                ad_out[(size_t)row * asH + t2] = vd;
            }
        }
    }
    if (EPI == 3) {
        float v[8][4];
#pragma unroll
        for (int ct = 0; ct < 8; ct++) {
            int col = ct * 16 + ln;
            float bv_ = bias[col];
#pragma unroll
            for (int reg = 0; reg < 4; reg++) {
                int row = rowb + reg;
                float r = (row < M) ? bf2f(Rres[(size_t)row * 128 + col]) : 0.f;
                v[ct][reg] = acc[ct][reg] + bv_ + r;
            }
        }
#pragma unroll
        for (int reg = 0; reg < 4; reg++) {
            float s = 0.f;
#pragma unroll
            for (int ct = 0; ct < 8; ct++) s += v[ct][reg];
            s += __shfl_xor(s, 1); s += __shfl_xor(s, 2);
            s += __shfl_xor(s, 4); s += __shfl_xor(s, 8);
            float mean = s * (1.f / 128.f);
            float s2 = 0.f;
#pragma unroll
            for (int ct = 0; ct < 8; ct++) { float d = v[ct][reg] - mean; s2 += d * d; }
            s2 += __shfl_xor(s2, 1); s2 += __shfl_xor(s2, 2);
            s2 += __shfl_xor(s2, 4); s2 += __shfl_xor(s2, 8);
            float rstd = rsqrtf(s2 * (1.f / 128.f) + 1e-5f);
            int row = rowb + reg;
            if (row < M) {
#pragma unroll
                for (int ct = 0; ct < 8; ct++) {
                    int col = ct * 16 + ln;
                    float o = (v[ct][reg] - mean) * rstd * lng[col] + lnb[col];
                    Qbout[(size_t)row * 128 + col] = __float2bfloat16(o);
                    if (Qout) Qout[(size_t)row * 128 + col] = o;
                }
            }
        }
    }
    if (EPI == 0 || EPI == 1 || EPI == 2) {
#pragma unroll
        for (int ct = 0; ct < 8; ct++) {
            int col = t2 * 128 + ct * 16 + ln;
            float bv_ = BIAS ? bias[col] : 0.f;
#pragma unroll
            for (int reg = 0; reg < 4; reg++) {
                int row = rowb + reg;
                if (row < M) {
                    float v = acc[ct][reg] + bv_;
                    if (EPI == 1) v = gelu_exact(v);
                    if (OUTBF16)
                        ((__hip_bfloat16*)Cv)[(size_t)row * Nc + col] = __float2bfloat16(v);
                    else
                        ((float*)Cv)[(size_t)row * Nc + col] = v;
                }
            }
        }
    }
}

template <int EPI, bool BIAS, bool OUTBF16, int NSPLIT, int KBC, int RT>
__global__ __launch_bounds__(256) void gemm_bf16_kernel(
    const short* __restrict__ A, const short* __restrict__ Bp,
    const float* __restrict__ bias, void* __restrict__ Cv,
    const float* __restrict__ a_s, const float* __restrict__ a_d,
    float* __restrict__ as_out, float* __restrict__ ad_out, int asH,
    const ushortT* __restrict__ Rres, const float* __restrict__ lng,
    const float* __restrict__ lnb, float* __restrict__ Qout,
    __hip_bfloat16* __restrict__ Qbout,
    int M, int K, int Nc) {
    __shared__ short Bs[(KBC > 0) ? KBC * 4096 : 8192];
    int t = threadIdx.x;
    int w = t >> 6, l = t & 63;
    int ln = l & 15, lq = l >> 4;
    const int ROWS = 64 * RT;
    int MBceil = (M + ROWS - 1) / ROWS;
    int bx = blockIdx.x;
    int xcd = bx & 7, idx = bx >> 3;
    int t2 = idx % NSPLIT;
    int mb = (idx / NSPLIT) * 8 + xcd;
    if (mb >= MBceil) return;
    int wbase = mb * ROWS + w * 16;

    bool aok[RT];
    const short* Ap[RT];
#pragma unroll
    for (int rt = 0; rt < RT; rt++) {
        int r = wbase + rt * 64 + ln;
        aok[rt] = r < M;
        Ap[rt] = A + (size_t)r * K + lq * 8;
    }

    f32x4 acc[RT][8];
#pragma unroll
    for (int rt = 0; rt < RT; rt++)
#pragma unroll
        for (int j = 0; j < 8; j++) acc[rt][j] = (f32x4){0.f, 0.f, 0.f, 0.f};

    if constexpr (KBC > 0) {
        {
            const uint4* src = (const uint4*)(Bp + (size_t)t2 * KBC * 4096);
            uint4* dst = (uint4*)Bs;
#pragma unroll
            for (int i = 0; i < KBC * 2; i++)
                dst[i * 256 + t] = src[i * 256 + t];
        }
        short8 af[RT][KBC];
#pragma unroll
        for (int rt = 0; rt < RT; rt++)
#pragma unroll
            for (int kb = 0; kb < KBC; kb++)
                af[rt][kb] = aok[rt] ? *(const short8*)(Ap[rt] + kb * 32)
                                     : (short8){0,0,0,0,0,0,0,0};
        __syncthreads();
#pragma unroll
        for (int kb = 0; kb < KBC; kb++)
#pragma unroll
            for (int ct = 0; ct < 8; ct++) {
                short8 bfr = *(const short8*)(Bs + ((ct * KBC + kb) * 64 + l) * 8);
#pragma unroll
                for (int rt = 0; rt < RT; rt++)
                    acc[rt][ct] = __builtin_amdgcn_mfma_f32_16x16x32_bf16(af[rt][kb], bfr, acc[rt][ct], 0, 0, 0);
            }
    } else {
        int kbc = K >> 5;
        int sct = t >> 5, spart = t & 31;
        auto stage = [&](int buf, int kb) {
            const uint4* src = (const uint4*)(Bp + ((size_t)(t2 * 8 + sct) * kbc + kb) * 512);
            uint4* dst = (uint4*)(Bs + buf * 4096 + sct * 512);
            dst[spart * 2]     = src[spart * 2];
            dst[spart * 2 + 1] = src[spart * 2 + 1];
        };
        stage(0, 0);
        __syncthreads();
        for (int kb = 0; kb < kbc; kb++) {
            if (kb + 1 < kbc) stage((kb + 1) & 1, kb + 1);
            short8 af[RT];
#pragma unroll
            for (int rt = 0; rt < RT; rt++)
                af[rt] = aok[rt] ? *(const short8*)(Ap[rt] + kb * 32)
                                 : (short8){0,0,0,0,0,0,0,0};
            const short* bsb = Bs + (kb & 1) * 4096;
#pragma unroll
            for (int ct = 0; ct < 8; ct++) {
                short8 bfr = *(const short8*)(bsb + (ct * 64 + l) * 8);
#pragma unroll
                for (int rt = 0; rt < RT; rt++)
                    acc[rt][ct] = __builtin_amdgcn_mfma_f32_16x16x32_bf16(af[rt], bfr, acc[rt][ct], 0, 0, 0);
            }
            __syncthreads();
        }
    }

#pragma unroll
    for (int rt = 0; rt < RT; rt++) {
        int rowb = wbase + rt * 64 + lq * 4;
        epi_store<EPI, BIAS, OUTBF16>(t2, acc[rt], M, Nc, rowb, ln, bias, Cv,
            a_s, a_d, as_out, ad_out, asH, Rres, lng, lnb, Qout, Qbout);
    }
}

// ---- GAT softmax-aggregate (online softmax, R11): 2 nodes/block ------------
// CPT == H: 128 threads cover H*128 cols; H=8 -> uint4 gathers, H=4 -> uint2.
template <int H>
__global__ __launch_bounds__(256) void gat_agg_fused_kernel(
    const ushortT* __restrict__ hpre, const float* __restrict__ as_,
    const float* __restrict__ ad_, const float* __restrict__ bias,
    const int* __restrict__ row_ptr, const int* __restrict__ edge_src,
    __hip_bfloat16* __restrict__ out, int n_nodes) {
    const int CPT = H;
    int node = blockIdx.x * 2 + (threadIdx.x >> 7);
    if (node >= n_nodes) return;
    int tt = threadIdx.x & 127;
    int c0 = tt * CPT;
    int hb = c0 >> 7;
    int start = row_ptr[node];
    int deg = row_ptr[node + 1] - start;
    float adn = ad_[(size_t)node * H + hb];
    float m = -1e30f, S = 0.f;
    float acc[CPT];
#pragma unroll
    for (int c = 0; c < CPT; c++) acc[c] = 0.f;
    for (int j = 0; j < deg; j++) {
        int s = edge_src[start + j];
        float e = as_[(size_t)s * H + hb] + adn;
        e = e > 0.f ? e : 0.2f * e;
        float mn = fmaxf(m, e);
        float sc = expf(m - mn);
        float wj = expf(e - mn);
        S = S * sc + wj;
        const ushortT* hp = hpre + (size_t)s * (H * 128) + c0;
        float hv[CPT];
        if (CPT == 8) {
            uint4 u = *(const uint4*)hp;
            hv[0] = bf2f((ushortT)(u.x & 0xffff)); hv[1] = bf2f((ushortT)(u.x >> 16));
            hv[2] = bf2f((ushortT)(u.y & 0xffff)); hv[3] = bf2f((ushortT)(u.y >> 16));
            hv[4] = bf2f((ushortT)(u.z & 0xffff)); hv[5] = bf2f((ushortT)(u.z >> 16));
            hv[6] = bf2f((ushortT)(u.w & 0xffff)); hv[7] = bf2f((ushortT)(u.w >> 16));
        } else {
            uint2 u = *(const uint2*)hp;
            hv[0] = bf2f((ushortT)(u.x & 0xffff)); hv[1] = bf2f((ushortT)(u.x >> 16));
            hv[2] = bf2f((ushortT)(u.y & 0xffff)); hv[3] = bf2f((ushortT)(u.y >> 16));
        }
#pragma unroll
        for (int c = 0; c < CPT; c++) acc[c] = acc[c] * sc + wj * hv[c];
        m = mn;
    }
    float inv = 1.f / (S + 1e-16f);
#pragma unroll
    for (int c = 0; c < CPT; c++)
        out[(size_t)node * (H * 128) + c0 + c] =
            __float2bfloat16(elu1(acc[c] * inv + bias[c0 + c]));
}

// ---------------- GCN aggregation (bf16 in) -> bf16 Qb only -----------------
__global__ __launch_bounds__(256) void gcn_agg_kernel(
    const ushortT* __restrict__ hp, const float* __restrict__ dinv,
    const float* __restrict__ b3, const int* __restrict__ row_ptr,
    const int* __restrict__ edge_src,
    __hip_bfloat16* __restrict__ outb, int n_nodes) {
    int node = blockIdx.x * 2 + (threadIdx.x >> 7);
    int c = threadIdx.x & 127;
    if (node >= n_nodes) return;
    int start = row_ptr[node];
    int deg = row_ptr[node + 1] - start;
    float dn = dinv[node];
    float acc = 0.f;
    for (int j = 0; j < deg; j++) {
        int s = edge_src[start + j];
        acc += dinv[s] * dn * bf2f(hp[(size_t)s * 128 + c]);
    }
    outb[(size_t)node * 128 + c] = __float2bfloat16(elu1(acc + b3[c]));
}

// ---------------- pooling ----------------
__global__ void pool1_kernel(const float* __restrict__ Q, const int* __restrict__ batch,
                             float* __restrict__ psum, float* __restrict__ pmax, int n_nodes) {
    int g = blockIdx.x, seg = blockIdx.y;
    int c = threadIdx.x;
    int lo, hi;
    {
        int l = 0, h = n_nodes;
        while (l < h) { int mid = (l + h) >> 1; if (batch[mid] < g) l = mid + 1; else h = mid; }
        lo = l;
        l = lo; h = n_nodes;
        while (l < h) { int mid = (l + h) >> 1; if (batch[mid] < g + 1) l = mid + 1; else h = mid; }
        hi = l;
    }
    int len = hi - lo;
    int a = lo + (int)((long)len * seg / 8);
    int b = lo + (int)((long)len * (seg + 1) / 8);
    float s = 0.f, mx = -INFINITY;
    for (int n = a; n < b; n++) {
        float v = Q[(size_t)n * 128 + c];
        s += v;
        mx = fmaxf(mx, v);
    }
    psum[(g * 8 + seg) * 128 + c] = s;
    pmax[(g * 8 + seg) * 128 + c] = mx;
}

__global__ void pool2_kernel(const float* __restrict__ psum, const float* __restrict__ pmax,
                             const int* __restrict__ batch,
                             const float* __restrict__ bn1g, const float* __restrict__ bn1b,
                             float* __restrict__ hc, int n_nodes) {
    int g = blockIdx.x;
    int c = threadIdx.x;
    int lo, hi;
    {
        int l = 0, h = n_nodes;
        while (l < h) { int mid = (l + h) >> 1; if (batch[mid] < g) l = mid + 1; else h = mid; }
        lo = l;
        l = lo; h = n_nodes;
        while (l < h) { int mid = (l + h) >> 1; if (batch[mid] < g + 1) l = mid + 1; else h = mid; }
        hi = l;
    }
    int cnt = hi - lo;
    float s = 0.f, mx = -INFINITY;
    for (int seg = 0; seg < 8; seg++) {
        s += psum[(g * 8 + seg) * 128 + c];
        mx = fmaxf(mx, pmax[(g * 8 + seg) * 128 + c]);
    }
    float hm = s / fmaxf((float)cnt, 1.f);
    float hx = (cnt > 0 && isfinite(mx)) ? mx : 0.f;
    const float bn_s = 0.99999500003749968f;
    hc[g * 256 + c]       = hm * bn_s * bn1g[c] + bn1b[c];
    hc[g * 256 + 128 + c] = hx * bn_s * bn1g[128 + c] + bn1b[128 + c];
}

__global__ void head_kernel(const float* __restrict__ hc,
                            const float* __restrict__ fc1w, const float* __restrict__ fc1b,
                            const float* __restrict__ bn2g, const float* __restrict__ bn2b,
                            const float* __restrict__ fc2w, const float* __restrict__ fc2b,
                            float* __restrict__ out) {
    int g = blockIdx.x;
    int j = threadIdx.x;
    const float bn_s = 0.99999500003749968f;
    float acc = fc1b[j];
    for (int i = 0; i < 256; i++) acc += hc[g * 256 + i] * fc1w[i * 64 + j];
    acc = elu1(acc);
    acc = acc * bn_s * bn2g[j] + bn2b[j];
    __shared__ float sv[64];
    sv[j] = acc;
    __syncthreads();
    if (j < 2) {
        float o = fc2b[j];
        for (int i = 0; i < 64; i++) o += sv[i] * fc2w[i * 2 + j];
        out[g * 2 + j] = o;
    }
}

// ---------------- launch ----------------
extern "C" void kernel_launch(void* const* d_in, const int* in_sizes, int n_in,
                              void* d_out, int out_size, void* d_ws, size_t ws_size,
                              hipStream_t stream) {
    const float* x    = (const float*)d_in[0];
    const int*   ei   = (const int*)d_in[1];
    const int*   batch= (const int*)d_in[2];
    const float* W1   = (const float*)d_in[3];
    const float* as1  = (const float*)d_in[4];
    const float* ad1  = (const float*)d_in[5];
    const float* b1   = (const float*)d_in[6];
    const float* W2   = (const float*)d_in[7];
    const float* as2  = (const float*)d_in[8];
    const float* ad2  = (const float*)d_in[9];
    const float* b2   = (const float*)d_in[10];
    const float* W3   = (const float*)d_in[11];
    const float* b3   = (const float*)d_in[12];
    const float* wv   = (const float*)d_in[17];
    const float* bv   = (const float*)d_in[18];
    const float* wo   = (const float*)d_in[19];
    const float* bo   = (const float*)d_in[20];
    const float* ln1g = (const float*)d_in[21];
    const float* ln1b = (const float*)d_in[22];
    const float* ln2g = (const float*)d_in[23];
    const float* ln2b = (const float*)d_in[24];
    const float* wf1  = (const float*)d_in[25];
    const float* bf1  = (const float*)d_in[26];
    const float* wf2  = (const float*)d_in[27];
    const float* bf2  = (const float*)d_in[28];
    const float* bn1g = (const float*)d_in[29];
    const float* bn1b = (const float*)d_in[30];
    const float* fc1w = (const float*)d_in[31];
    const float* fc1b = (const float*)d_in[32];
    const float* bn2g = (const float*)d_in[33];
    const float* bn2b = (const float*)d_in[34];
    const float* fc2w = (const float*)d_in[35];
    const float* fc2b = (const float*)d_in[36];
    float* out = (float*)d_out;

    // ---- workspace layout (bytes), peak ~227 MB ----
    char* wsb = (char*)d_ws;
    short* xb    = (short*)wsb;                        // [N,128] bf16
    short* h1pre = (short*)(wsb + 12800000);           // [N,1024] bf16
    short* h2pre = (short*)(wsb + 12800000);           // [N,512] (h1pre dead)
    short* h3pre = (short*)(wsb + 12800000);           // [N,128] (h2pre dead)
    short* FFb   = (short*)(wsb + 25600000);           // [N,512] bf16 (transformer)
    short* bh1   = (short*)(wsb + 115200000);          // [N,1024] bf16
    short* bh2   = (short*)(wsb + 115200000);          // [N,512] (bh1 dead)
    float* fQ    = (float*)(wsb + 128000000);          // [N,128] fp32 (final state only)
    short* Qb    = (short*)(wsb + 153600000);          // [N,128] bf16 transformer state
    char* tail = wsb + 217600000;
    short* W1p  = (short*)tail;  tail += 262144;       // 128x1024
    short* W2p  = (short*)tail;  tail += 1048576;      // 1024x512
    short* W3p  = (short*)tail;  tail += 131072;       // 512x128
    short* Wvop = (short*)tail;  tail += 196608;       // 6 x 128x128
    short* wf1p = (short*)tail;  tail += 786432;       // 6 x 128x512
    short* wf2p = (short*)tail;  tail += 786432;       // 6 x 512x128
    float* Wvo  = (float*)tail;  tail += 393216;       // 6 x 128x128 fp32
    float* bvo  = (float*)tail;  tail += 3072;         // 6 x 128 fp32
    float* fAS  = (float*)tail;  tail += 1600000;      // [N,8]
    float* fAD  = (float*)tail;  tail += 1600000;      // [N,8]
    float* fDv  = (float*)tail;  tail += 200000;
    float* psum = (float*)tail;  tail += 262144;
    float* pmax = (float*)tail;  tail += 262144;
    float* fHC  = (float*)tail;  tail += 65536;
    int* iDeg   = (int*)tail;    tail += 200000;
    int* iRP    = (int*)tail;    tail += 200004;
    int* iCur   = (int*)tail;    tail += 200000;
    int* iES    = (int*)tail;    tail += 1000000;

    hipMemsetAsync(iDeg, 0, NN * sizeof(int), stream);
    hipMemsetAsync(iCur, 0, NN * sizeof(int), stream);

    count_deg_kernel<<<(ET + 255) / 256, 256, 0, stream>>>(ei, iDeg);
    scan_kernel<<<1, 1024, 0, stream>>>(iDeg, iRP, NN);
    fill_csr_kernel<<<(ET + 255) / 256, 256, 0, stream>>>(ei, iRP, iCur, iES);
    dinv_kernel<<<(NN + 255) / 256, 256, 0, stream>>>(iRP, fDv);

    wvwo_kernel<<<dim3(64, 6), 256, 0, stream>>>(wv, wo, bv, bo, Wvo, bvo);
    auto bprep = [&](const float* B, short* Bp, int K, int N, int ldb, long sStride, int layers) {
        int total = (K >> 5) * (N >> 4) * 64;
        dim3 grid((total + 255) / 256, layers);
        bprep_kernel<<<grid, 256, 0, stream>>>(B, Bp, K, N, ldb, sStride);
    };
    bprep(W1, W1p, 128, 1024, 1024, 0, 1);
    bprep(W2, W2p, 1024, 512, 512, 0, 1);
    bprep(W3, W3p, 512, 128, 128, 0, 1);
    bprep(Wvo, Wvop, 128, 128, 128, 16384, 6);
    bprep(wf1, wf1p, 128, 512, 512, 65536, 6);
    bprep(wf2, wf2p, 512, 128, 128, 65536, 6);
    cast_bf16_kernel<<<(NN * 128 / 4 + 255) / 256, 256, 0, stream>>>(x, xb, NN * 128 / 4);

    const int MB64p  = (((NN + 63) / 64 + 7) / 8) * 8;     // 784  (RT=1 blocks)
    const int MB128p = (((NN + 127) / 128 + 7) / 8) * 8;   // 392  (RT=2 blocks)

    // ---- GAT layer 1 (K=128, 8 column tiles, LDS-B, RT=1) ----
    gemm_bf16_kernel<2, false, true, 8, 4, 1><<<MB64p * 8, 256, 0, stream>>>(
        xb, W1p, nullptr, h1pre, as1, ad1, fAS, fAD, 8,
        nullptr, nullptr, nullptr, nullptr, nullptr, NN, 128, 1024);
    gat_agg_fused_kernel<8><<<(NN + 1) / 2, 256, 0, stream>>>(
        (const ushortT*)h1pre, fAS, fAD, b1, iRP, iES, (__hip_bfloat16*)bh1, NN);
    // ---- GAT layer 2 (K=1024, 4 column tiles, LDS-B dbuf, RT=2) ----
    gemm_bf16_kernel<2, false, true, 4, 0, 2><<<MB128p * 4, 256, 0, stream>>>(
        bh1, W2p, nullptr, h2pre, as2, ad2, fAS, fAD, 4,
        nullptr, nullptr, nullptr, nullptr, nullptr, NN, 1024, 512);
    gat_agg_fused_kernel<4><<<(NN + 1) / 2, 256, 0, stream>>>(
        (const ushortT*)h2pre, fAS, fAD, b2, iRP, iES, (__hip_bfloat16*)bh2, NN);
    // ---- GCN (RT=2) ----
    gemm_bf16_kernel<0, false, true, 1, 0, 2><<<MB128p, 256, 0, stream>>>(
        bh2, W3p, nullptr, h3pre, nullptr, nullptr, nullptr, nullptr, 0,
        nullptr, nullptr, nullptr, nullptr, nullptr, NN, 512, 128);
    gcn_agg_kernel<<<(NN + 1) / 2, 256, 0, stream>>>(
        (const ushortT*)h3pre, fDv, b3, iRP, iES, (__hip_bfloat16*)Qb, NN);
    // ---- Transformer (seq_len=1; attn folded; bf16 residual state in Qb) ----
    for (int l = 0; l < LL; l++) {
        gemm_bf16_kernel<3, true, false, 1, 4, 1><<<MB64p, 256, 0, stream>>>(
            Qb, Wvop + l * 16384, bvo + l * 128, nullptr, nullptr, nullptr, nullptr, nullptr, 0,
            (const ushortT*)Qb, ln1g + l * 128, ln1b + l * 128, nullptr, (__hip_bfloat16*)Qb,
            NN, 128, 128);
        gemm_bf16_kernel<1, true, true, 4, 4, 1><<<MB64p * 4, 256, 0, stream>>>(
            Qb, wf1p + l * 65536, bf1 + l * 512, FFb, nullptr, nullptr, nullptr, nullptr, 0,
            nullptr, nullptr, nullptr, nullptr, nullptr, NN, 128, 512);
        gemm_bf16_kernel<3, true, false, 1, 0, 2><<<MB128p, 256, 0, stream>>>(
            FFb, wf2p + l * 65536, bf2 + l * 128, nullptr, nullptr, nullptr, nullptr, nullptr, 0,
            (const ushortT*)Qb, ln2g + l * 128, ln2b + l * 128,
            (l == LL - 1) ? fQ : nullptr, (__hip_bfloat16*)Qb, NN, 512, 128);
    }
    // ---- pool + head ----
    pool1_kernel<<<dim3(GG, 8), 128, 0, stream>>>(fQ, batch, psum, pmax, NN);
    pool2_kernel<<<GG, 128, 0, stream>>>(psum, pmax, batch, bn1g, bn1b, fHC, NN);
    head_kernel<<<GG, 64, 0, stream>>>(fHC, fc1w, fc1b, bn2g, bn2b, fc2w, fc2b, out);
}

// Round 15
// 1410.675 us; speedup vs baseline: 1.0130x; 1.0003x over previous
//
#include <hip/hip_runtime.h>
#include <hip/hip_bf16.h>
#include <math.h>

#define NN 50000
#define EE 200000
#define ET 250000   // EE + NN self loops
#define GG 64
#define LL 6

using short8 = __attribute__((ext_vector_type(8))) short;
using f32x4  = __attribute__((ext_vector_type(4))) float;
typedef unsigned short ushortT;

__device__ __forceinline__ float elu1(float x) { return x > 0.f ? x : expm1f(x); }
__device__ __forceinline__ float gelu_exact(float x) {
    return 0.5f * x * (1.f + erff(x * 0.70710678118654752440f));
}
__device__ __forceinline__ short f2bf(float f) {
    __hip_bfloat16 h = __float2bfloat16(f);
    return *reinterpret_cast<short*>(&h);
}
__device__ __forceinline__ float bf2f(ushortT u) {
    return __uint_as_float(((unsigned)u) << 16);
}

// ---------------- CSR build ----------------
__global__ void count_deg_kernel(const int* __restrict__ ei, int* __restrict__ deg) {
    int e = blockIdx.x * 256 + threadIdx.x;
    if (e >= ET) return;
    int dst = (e < EE) ? ei[EE + e] : (e - EE);
    atomicAdd(&deg[dst], 1);
}

__global__ void scan_kernel(const int* __restrict__ deg, int* __restrict__ row_ptr, int n) {
    __shared__ int s[1024];
    int tid = threadIdx.x;
    const int per = (n + 1023) / 1024;
    int lo = tid * per, hi = min(lo + per, n);
    int sum = 0;
    for (int i = lo; i < hi; i++) sum += deg[i];
    s[tid] = sum;
    __syncthreads();
    for (int off = 1; off < 1024; off <<= 1) {
        int t = (tid >= off) ? s[tid - off] : 0;
        __syncthreads();
        s[tid] += t;
        __syncthreads();
    }
    int run = s[tid] - sum;
    for (int i = lo; i < hi; i++) { row_ptr[i] = run; run += deg[i]; }
    if (tid == 1023) row_ptr[n] = s[1023];
}

__global__ void fill_csr_kernel(const int* __restrict__ ei, const int* __restrict__ row_ptr,
                                int* __restrict__ cursor, int* __restrict__ edge_src) {
    int e = blockIdx.x * 256 + threadIdx.x;
    if (e >= ET) return;
    int src, dst;
    if (e < EE) { src = ei[e]; dst = ei[EE + e]; }
    else        { src = e - EE; dst = e - EE; }
    int pos = atomicAdd(&cursor[dst], 1);
    edge_src[row_ptr[dst] + pos] = src;
}

__global__ void dinv_kernel(const int* __restrict__ row_ptr, float* __restrict__ dinv) {
    int n = blockIdx.x * 256 + threadIdx.x;
    if (n >= NN) return;
    int d = row_ptr[n + 1] - row_ptr[n];
    dinv[n] = (d > 0) ? rsqrtf((float)d) : 0.f;
}

// ---- fold wv into wo: Wvo = wv@wo, bvo = bv@wo + bo (fp32, exact) ----
__global__ void wvwo_kernel(const float* __restrict__ wv, const float* __restrict__ wo,
                            const float* __restrict__ bv, const float* __restrict__ bo,
                            float* __restrict__ Wvo, float* __restrict__ bvo) {
    int l = blockIdx.y;
    const float* Wv = wv + l * 16384;
    const float* Wo = wo + l * 16384;
    int tid = blockIdx.x * 256 + threadIdx.x;
    if (tid < 16384) {
        int r = tid >> 7, c = tid & 127;
        float s = 0.f;
        for (int k = 0; k < 128; k++) s += Wv[r * 128 + k] * Wo[k * 128 + c];
        Wvo[l * 16384 + tid] = s;
    }
    if (blockIdx.x == 0 && threadIdx.x < 128) {
        int c = threadIdx.x;
        float s = bo[l * 128 + c];
        for (int k = 0; k < 128; k++) s += bv[l * 128 + k] * Wo[k * 128 + c];
        bvo[l * 128 + c] = s;
    }
}

// ---- weight prep: fp32 [K,N] (ldb) -> bf16 MFMA B-fragment order ----
__global__ void bprep_kernel(const float* __restrict__ B, short* __restrict__ Bp,
                             int K, int N, int ldb, long srcStride) {
    int layer = blockIdx.y;
    const float* Bsrc = B + srcStride * layer;
    short* Bd = Bp + (size_t)K * N * layer;
    int total = (K >> 5) * (N >> 4) * 64;
    int tid = blockIdx.x * 256 + threadIdx.x;
    if (tid >= total) return;
    int l = tid & 63;
    int rest = tid >> 6;
    int kbc = K >> 5;
    int kb = rest % kbc;
    int c16 = rest / kbc;
    int n = c16 * 16 + (l & 15);
    int kbase = kb * 32 + (l >> 4) * 8;
    short v[8];
#pragma unroll
    for (int j = 0; j < 8; j++) v[j] = f2bf(Bsrc[(size_t)(kbase + j) * ldb + n]);
    *(uint4*)(Bd + (size_t)tid * 8) = *(uint4*)v;
}

__global__ void cast_bf16_kernel(const float* __restrict__ in, short* __restrict__ out, int n4) {
    int i = blockIdx.x * 256 + threadIdx.x;
    if (i >= n4) return;
    float4 v = *(const float4*)(in + (size_t)i * 4);
    short s[4] = { f2bf(v.x), f2bf(v.y), f2bf(v.z), f2bf(v.w) };
    *(uint2*)(out + (size_t)i * 4) = *(uint2*)s;
}

// ---------------- MFMA GEMM, LDS B-staging, XCD swizzle (R11 config) --------
// 64-row blocks, 16 rows/wave, RT=1 (R5/R8/R14: multi-acc variants lose more
// occupancy than they save). KBC>0: whole B tile staged once, one barrier.
// KBC==0: 8KB dbuf slices, one barrier/kb. xcd = bx&7 keeps one row band's
// NSPLIT column tiles on one XCD L2 (R8: GAT2 FETCH 203->61 MB).
// EPI: 0 plain, 1 gelu, 2 asad + store, 3 residual(bf16)+LN in-place (Nc==128)
template <int EPI, bool BIAS, bool OUTBF16>
__device__ __forceinline__ void epi_store(
    int t2, f32x4 (&acc)[8], int M, int Nc, int rowb, int ln,
    const float* __restrict__ bias, void* __restrict__ Cv,
    const float* __restrict__ a_s, const float* __restrict__ a_d,
    float* __restrict__ as_out, float* __restrict__ ad_out, int asH,
    const ushortT* __restrict__ Rres, const float* __restrict__ lng,
    const float* __restrict__ lnb, float* __restrict__ Qout,
    __hip_bfloat16* __restrict__ Qbout) {
    if (EPI == 2) {
        const float* asv = a_s + t2 * 128;
        const float* adv = a_d + t2 * 128;
#pragma unroll
        for (int reg = 0; reg < 4; reg++) {
            float vs = 0.f, vd = 0.f;
#pragma unroll
            for (int ct = 0; ct < 8; ct++) {
                int colL = ct * 16 + ln;
                float av = acc[ct][reg];
                vs += av * asv[colL];
                vd += av * adv[colL];
            }
            vs += __shfl_xor(vs, 1); vs += __shfl_xor(vs, 2);
            vs += __shfl_xor(vs, 4); vs += __shfl_xor(vs, 8);
            vd += __shfl_xor(vd, 1); vd += __shfl_xor(vd, 2);
            vd += __shfl_xor(vd, 4); vd += __shfl_xor(vd, 8);
            int row = rowb + reg;
            if (ln == 0 && row < M) {
                as_out[(size_t)row * asH + t2] = vs;
                ad_out[(size_t)row * asH + t2] = vd;
            }
        }
    }
    if (EPI == 3) {
        float v[8][4];
#pragma unroll
        for (int ct = 0; ct < 8; ct++) {
            int col = ct * 16 + ln;
            float bv_ = bias[col];
#pragma unroll
            for (int reg = 0; reg < 4; reg++) {
                int row = rowb + reg;
                float r = (row < M) ? bf2f(Rres[(size_t)row * 128 + col]) : 0.f;
                v[ct][reg] = acc[ct][reg] + bv_ + r;
            }
        }
#pragma unroll
        for (int reg = 0; reg < 4; reg++) {
            float s = 0.f;
#pragma unroll
            for (int ct = 0; ct < 8; ct++) s += v[ct][reg];
            s += __shfl_xor(s, 1); s += __shfl_xor(s, 2);
            s += __shfl_xor(s, 4); s += __shfl_xor(s, 8);
            float mean = s * (1.f / 128.f);
            float s2 = 0.f;
#pragma unroll
            for (int ct = 0; ct < 8; ct++) { float d = v[ct][reg] - mean; s2 += d * d; }
            s2 += __shfl_xor(s2, 1); s2 += __shfl_xor(s2, 2);
            s2 += __shfl_xor(s2, 4); s2 += __shfl_xor(s2, 8);
            float rstd = rsqrtf(s2 * (1.f / 128.f) + 1e-5f);
            int row = rowb + reg;
            if (row < M) {
#pragma unroll
                for (int ct = 0; ct < 8; ct++) {
                    int col = ct * 16 + ln;
                    float o = (v[ct][reg] - mean) * rstd * lng[col] + lnb[col];
                    Qbout[(size_t)row * 128 + col] = __float2bfloat16(o);
                    if (Qout) Qout[(size_t)row * 128 + col] = o;
                }
            }
        }
    }
    if (EPI == 0 || EPI == 1 || EPI == 2) {
#pragma unroll
        for (int ct = 0; ct < 8; ct++) {
            int col = t2 * 128 + ct * 16 + ln;
            float bv_ = BIAS ? bias[col] : 0.f;
#pragma unroll
            for (int reg = 0; reg < 4; reg++) {
                int row = rowb + reg;
                if (row < M) {
                    float v = acc[ct][reg] + bv_;
                    if (EPI == 1) v = gelu_exact(v);
                    if (OUTBF16)
                        ((__hip_bfloat16*)Cv)[(size_t)row * Nc + col] = __float2bfloat16(v);
                    else
                        ((float*)Cv)[(size_t)row * Nc + col] = v;
                }
            }
        }
    }
}

template <int EPI, bool BIAS, bool OUTBF16, int NSPLIT, int KBC>
__global__ __launch_bounds__(256) void gemm_bf16_kernel(
    const short* __restrict__ A, const short* __restrict__ Bp,
    const float* __restrict__ bias, void* __restrict__ Cv,
    const float* __restrict__ a_s, const float* __restrict__ a_d,
    float* __restrict__ as_out, float* __restrict__ ad_out, int asH,
    const ushortT* __restrict__ Rres, const float* __restrict__ lng,
    const float* __restrict__ lnb, float* __restrict__ Qout,
    __hip_bfloat16* __restrict__ Qbout,
    int M, int K, int Nc) {
    __shared__ short Bs[(KBC > 0) ? KBC * 4096 : 8192];
    int t = threadIdx.x;
    int w = t >> 6, l = t & 63;
    int ln = l & 15, lq = l >> 4;
    int MBceil = (M + 63) >> 6;
    int bx = blockIdx.x;
    int xcd = bx & 7, idx = bx >> 3;
    int t2 = idx % NSPLIT;
    int mb = (idx / NSPLIT) * 8 + xcd;
    if (mb >= MBceil) return;
    int bm = mb * 64 + w * 16;
    int arow = bm + ln;
    bool aok = arow < M;
    int rowb = bm + lq * 4;
    const short* Ap = A + (size_t)arow * K + lq * 8;

    f32x4 acc[8];
#pragma unroll
    for (int j = 0; j < 8; j++) acc[j] = (f32x4){0.f, 0.f, 0.f, 0.f};

    if constexpr (KBC > 0) {
        {
            const uint4* src = (const uint4*)(Bp + (size_t)t2 * KBC * 4096);
            uint4* dst = (uint4*)Bs;
#pragma unroll
            for (int i = 0; i < KBC * 2; i++)
                dst[i * 256 + t] = src[i * 256 + t];
        }
        short8 af[KBC];
#pragma unroll
        for (int kb = 0; kb < KBC; kb++)
            af[kb] = aok ? *(const short8*)(Ap + kb * 32) : (short8){0,0,0,0,0,0,0,0};
        __syncthreads();
#pragma unroll
        for (int kb = 0; kb < KBC; kb++)
#pragma unroll
            for (int ct = 0; ct < 8; ct++) {
                short8 bfr = *(const short8*)(Bs + ((ct * KBC + kb) * 64 + l) * 8);
                acc[ct] = __builtin_amdgcn_mfma_f32_16x16x32_bf16(af[kb], bfr, acc[ct], 0, 0, 0);
            }
    } else {
        int kbc = K >> 5;
        int sct = t >> 5, spart = t & 31;
        auto stage = [&](int buf, int kb) {
            const uint4* src = (const uint4*)(Bp + ((size_t)(t2 * 8 + sct) * kbc + kb) * 512);
            uint4* dst = (uint4*)(Bs + buf * 4096 + sct * 512);
            dst[spart * 2]     = src[spart * 2];
            dst[spart * 2 + 1] = src[spart * 2 + 1];
        };
        stage(0, 0);
        __syncthreads();
        for (int kb = 0; kb < kbc; kb++) {
            if (kb + 1 < kbc) stage((kb + 1) & 1, kb + 1);
            short8 af = aok ? *(const short8*)(Ap + kb * 32) : (short8){0,0,0,0,0,0,0,0};
            const short* bsb = Bs + (kb & 1) * 4096;
#pragma unroll
            for (int ct = 0; ct < 8; ct++) {
                short8 bfr = *(const short8*)(bsb + (ct * 64 + l) * 8);
                acc[ct] = __builtin_amdgcn_mfma_f32_16x16x32_bf16(af, bfr, acc[ct], 0, 0, 0);
            }
            __syncthreads();
        }
    }

    epi_store<EPI, BIAS, OUTBF16>(t2, acc, M, Nc, rowb, ln, bias, Cv,
        a_s, a_d, as_out, ad_out, asH, Rres, lng, lnb, Qout, Qbout);
}

// ---------------- fused FFN: gelu(h@wf1+bf1)@wf2 + bf2 + resid + LN2 --------
// 64 rows/block, 16/wave. Hidden chunk (16x128) round-trips through per-wave
// LDS (C-layout -> A-frags; wave-local, no barrier — R9-validated pattern).
// kb order c*4+kb2 = 0..15 matches the split wf2 gemm -> bit-identical result.
// B-frags (wf1p/wf2p, 256 KB/layer) read straight from L2.
__global__ __launch_bounds__(256) void ffn_fused_kernel(
    const short* __restrict__ Qb, const short* __restrict__ wf1p_l,
    const float* __restrict__ bf1_l, const short* __restrict__ wf2p_l,
    const float* __restrict__ bf2_l, const float* __restrict__ lng,
    const float* __restrict__ lnb, float* __restrict__ Qout,
    int M) {
    __shared__ short Hs[4][16][130];
    int t = threadIdx.x;
    int w = t >> 6, l = t & 63;
    int ln = l & 15, lq = l >> 4;
    int wbase = blockIdx.x * 64 + w * 16;
    int arow = wbase + ln;
    bool aok = arow < M;
    const short* Ap = Qb + (size_t)arow * 128 + lq * 8;
    short (*Hw)[130] = Hs[w];

    short8 af[4];
#pragma unroll
    for (int kb = 0; kb < 4; kb++)
        af[kb] = aok ? *(const short8*)(Ap + kb * 32) : (short8){0,0,0,0,0,0,0,0};

    f32x4 out[8];
#pragma unroll
    for (int j = 0; j < 8; j++) out[j] = (f32x4){0.f, 0.f, 0.f, 0.f};

#pragma unroll
    for (int c = 0; c < 4; c++) {
        // hidden chunk: gelu(h @ wf1_c + bf1_c) -> per-wave LDS (bf16)
#pragma unroll
        for (int ct = 0; ct < 8; ct++) {
            f32x4 h4 = (f32x4){0.f, 0.f, 0.f, 0.f};
#pragma unroll
            for (int kb = 0; kb < 4; kb++) {
                short8 bfr = *(const short8*)(wf1p_l + (((c * 8 + ct) * 4 + kb) * 64 + l) * 8);
                h4 = __builtin_amdgcn_mfma_f32_16x16x32_bf16(af[kb], bfr, h4, 0, 0, 0);
            }
            int col = ct * 16 + ln;
            float bb = bf1_l[c * 128 + col];
#pragma unroll
            for (int reg = 0; reg < 4; reg++)
                Hw[lq * 4 + reg][col] = f2bf(gelu_exact(h4[reg] + bb));
        }
        // out += hidden_c @ wf2_c  (kb global = c*4+kb2, same order as split)
        short8 hf[4];
#pragma unroll
        for (int kb2 = 0; kb2 < 4; kb2++)
            hf[kb2] = *(const short8*)&Hw[ln][kb2 * 32 + lq * 8];
#pragma unroll
        for (int ct = 0; ct < 8; ct++)
#pragma unroll
            for (int kb2 = 0; kb2 < 4; kb2++) {
                short8 bfr = *(const short8*)(wf2p_l + ((ct * 16 + c * 4 + kb2) * 64 + l) * 8);
                out[ct] = __builtin_amdgcn_mfma_f32_16x16x32_bf16(hf[kb2], bfr, out[ct], 0, 0, 0);
            }
    }

    // epilogue: + bf2 + residual(Qb bf16) + LayerNorm -> Qb (in place), fQ opt.
    int rowb = wbase + lq * 4;
    float v[8][4];
#pragma unroll
    for (int ct = 0; ct < 8; ct++) {
        int col = ct * 16 + ln;
        float bv_ = bf2_l[col];
#pragma unroll
        for (int reg = 0; reg < 4; reg++) {
            int row = rowb + reg;
            float r = (row < M) ? bf2f(((const ushortT*)Qb)[(size_t)row * 128 + col]) : 0.f;
            v[ct][reg] = out[ct][reg] + bv_ + r;
        }
    }
#pragma unroll
    for (int reg = 0; reg < 4; reg++) {
        float s = 0.f;
#pragma unroll
        for (int ct = 0; ct < 8; ct++) s += v[ct][reg];
        s += __shfl_xor(s, 1); s += __shfl_xor(s, 2);
        s += __shfl_xor(s, 4); s += __shfl_xor(s, 8);
        float mean = s * (1.f / 128.f);
        float s2 = 0.f;
#pragma unroll
        for (int ct = 0; ct < 8; ct++) { float d = v[ct][reg] - mean; s2 += d * d; }
        s2 += __shfl_xor(s2, 1); s2 += __shfl_xor(s2, 2);
        s2 += __shfl_xor(s2, 4); s2 += __shfl_xor(s2, 8);
        float rstd = rsqrtf(s2 * (1.f / 128.f) + 1e-5f);
        int row = rowb + reg;
        if (row < M) {
#pragma unroll
            for (int ct = 0; ct < 8; ct++) {
                int col = ct * 16 + ln;
                float o = (v[ct][reg] - mean) * rstd * lng[col] + lnb[col];
                ((__hip_bfloat16*)Qb)[(size_t)row * 128 + col] = __float2bfloat16(o);
                if (Qout) Qout[(size_t)row * 128 + col] = o;
            }
        }
    }
}

// ---- GAT softmax-aggregate (online softmax, R11): 2 nodes/block ------------
template <int H>
__global__ __launch_bounds__(256) void gat_agg_fused_kernel(
    const ushortT* __restrict__ hpre, const float* __restrict__ as_,
    const float* __restrict__ ad_, const float* __restrict__ bias,
    const int* __restrict__ row_ptr, const int* __restrict__ edge_src,
    __hip_bfloat16* __restrict__ out, int n_nodes) {
    const int CPT = H;
    int node = blockIdx.x * 2 + (threadIdx.x >> 7);
    if (node >= n_nodes) return;
    int tt = threadIdx.x & 127;
    int c0 = tt * CPT;
    int hb = c0 >> 7;
    int start = row_ptr[node];
    int deg = row_ptr[node + 1] - start;
    float adn = ad_[(size_t)node * H + hb];
    float m = -1e30f, S = 0.f;
    float acc[CPT];
#pragma unroll
    for (int c = 0; c < CPT; c++) acc[c] = 0.f;
    for (int j = 0; j < deg; j++) {
        int s = edge_src[start + j];
        float e = as_[(size_t)s * H + hb] + adn;
        e = e > 0.f ? e : 0.2f * e;
        float mn = fmaxf(m, e);
        float sc = expf(m - mn);
        float wj = expf(e - mn);
        S = S * sc + wj;
        const ushortT* hp = hpre + (size_t)s * (H * 128) + c0;
        float hv[CPT];
        if (CPT == 8) {
            uint4 u = *(const uint4*)hp;
            hv[0] = bf2f((ushortT)(u.x & 0xffff)); hv[1] = bf2f((ushortT)(u.x >> 16));
            hv[2] = bf2f((ushortT)(u.y & 0xffff)); hv[3] = bf2f((ushortT)(u.y >> 16));
            hv[4] = bf2f((ushortT)(u.z & 0xffff)); hv[5] = bf2f((ushortT)(u.z >> 16));
            hv[6] = bf2f((ushortT)(u.w & 0xffff)); hv[7] = bf2f((ushortT)(u.w >> 16));
        } else {
            uint2 u = *(const uint2*)hp;
            hv[0] = bf2f((ushortT)(u.x & 0xffff)); hv[1] = bf2f((ushortT)(u.x >> 16));
            hv[2] = bf2f((ushortT)(u.y & 0xffff)); hv[3] = bf2f((ushortT)(u.y >> 16));
        }
#pragma unroll
        for (int c = 0; c < CPT; c++) acc[c] = acc[c] * sc + wj * hv[c];
        m = mn;
    }
    float inv = 1.f / (S + 1e-16f);
#pragma unroll
    for (int c = 0; c < CPT; c++)
        out[(size_t)node * (H * 128) + c0 + c] =
            __float2bfloat16(elu1(acc[c] * inv + bias[c0 + c]));
}

// ---------------- GCN aggregation (bf16 in) -> bf16 Qb only -----------------
__global__ __launch_bounds__(256) void gcn_agg_kernel(
    const ushortT* __restrict__ hp, const float* __restrict__ dinv,
    const float* __restrict__ b3, const int* __restrict__ row_ptr,
    const int* __restrict__ edge_src,
    __hip_bfloat16* __restrict__ outb, int n_nodes) {
    int node = blockIdx.x * 2 + (threadIdx.x >> 7);
    int c = threadIdx.x & 127;
    if (node >= n_nodes) return;
    int start = row_ptr[node];
    int deg = row_ptr[node + 1] - start;
    float dn = dinv[node];
    float acc = 0.f;
    for (int j = 0; j < deg; j++) {
        int s = edge_src[start + j];
        acc += dinv[s] * dn * bf2f(hp[(size_t)s * 128 + c]);
    }
    outb[(size_t)node * 128 + c] = __float2bfloat16(elu1(acc + b3[c]));
}

// ---------------- pooling ----------------
__global__ void pool1_kernel(const float* __restrict__ Q, const int* __restrict__ batch,
                             float* __restrict__ psum, float* __restrict__ pmax, int n_nodes) {
    int g = blockIdx.x, seg = blockIdx.y;
    int c = threadIdx.x;
    int lo, hi;
    {
        int l = 0, h = n_nodes;
        while (l < h) { int mid = (l + h) >> 1; if (batch[mid] < g) l = mid + 1; else h = mid; }
        lo = l;
        l = lo; h = n_nodes;
        while (l < h) { int mid = (l + h) >> 1; if (batch[mid] < g + 1) l = mid + 1; else h = mid; }
        hi = l;
    }
    int len = hi - lo;
    int a = lo + (int)((long)len * seg / 8);
    int b = lo + (int)((long)len * (seg + 1) / 8);
    float s = 0.f, mx = -INFINITY;
    for (int n = a; n < b; n++) {
        float v = Q[(size_t)n * 128 + c];
        s += v;
        mx = fmaxf(mx, v);
    }
    psum[(g * 8 + seg) * 128 + c] = s;
    pmax[(g * 8 + seg) * 128 + c] = mx;
}

__global__ void pool2_kernel(const float* __restrict__ psum, const float* __restrict__ pmax,
                             const int* __restrict__ batch,
                             const float* __restrict__ bn1g, const float* __restrict__ bn1b,
                             float* __restrict__ hc, int n_nodes) {
    int g = blockIdx.x;
    int c = threadIdx.x;
    int lo, hi;
    {
        int l = 0, h = n_nodes;
        while (l < h) { int mid = (l + h) >> 1; if (batch[mid] < g) l = mid + 1; else h = mid; }
        lo = l;
        l = lo; h = n_nodes;
        while (l < h) { int mid = (l + h) >> 1; if (batch[mid] < g + 1) l = mid + 1; else h = mid; }
        hi = l;
    }
    int cnt = hi - lo;
    float s = 0.f, mx = -INFINITY;
    for (int seg = 0; seg < 8; seg++) {
        s += psum[(g * 8 + seg) * 128 + c];
        mx = fmaxf(mx, pmax[(g * 8 + seg) * 128 + c]);
    }
    float hm = s / fmaxf((float)cnt, 1.f);
    float hx = (cnt > 0 && isfinite(mx)) ? mx : 0.f;
    const float bn_s = 0.99999500003749968f;
    hc[g * 256 + c]       = hm * bn_s * bn1g[c] + bn1b[c];
    hc[g * 256 + 128 + c] = hx * bn_s * bn1g[128 + c] + bn1b[128 + c];
}

__global__ void head_kernel(const float* __restrict__ hc,
                            const float* __restrict__ fc1w, const float* __restrict__ fc1b,
                            const float* __restrict__ bn2g, const float* __restrict__ bn2b,
                            const float* __restrict__ fc2w, const float* __restrict__ fc2b,
                            float* __restrict__ out) {
    int g = blockIdx.x;
    int j = threadIdx.x;
    const float bn_s = 0.99999500003749968f;
    float acc = fc1b[j];
    for (int i = 0; i < 256; i++) acc += hc[g * 256 + i] * fc1w[i * 64 + j];
    acc = elu1(acc);
    acc = acc * bn_s * bn2g[j] + bn2b[j];
    __shared__ float sv[64];
    sv[j] = acc;
    __syncthreads();
    if (j < 2) {
        float o = fc2b[j];
        for (int i = 0; i < 64; i++) o += sv[i] * fc2w[i * 2 + j];
        out[g * 2 + j] = o;
    }
}

// ---------------- launch ----------------
extern "C" void kernel_launch(void* const* d_in, const int* in_sizes, int n_in,
                              void* d_out, int out_size, void* d_ws, size_t ws_size,
                              hipStream_t stream) {
    const float* x    = (const float*)d_in[0];
    const int*   ei   = (const int*)d_in[1];
    const int*   batch= (const int*)d_in[2];
    const float* W1   = (const float*)d_in[3];
    const float* as1  = (const float*)d_in[4];
    const float* ad1  = (const float*)d_in[5];
    const float* b1   = (const float*)d_in[6];
    const float* W2   = (const float*)d_in[7];
    const float* as2  = (const float*)d_in[8];
    const float* ad2  = (const float*)d_in[9];
    const float* b2   = (const float*)d_in[10];
    const float* W3   = (const float*)d_in[11];
    const float* b3   = (const float*)d_in[12];
    const float* wv   = (const float*)d_in[17];
    const float* bv   = (const float*)d_in[18];
    const float* wo   = (const float*)d_in[19];
    const float* bo   = (const float*)d_in[20];
    const float* ln1g = (const float*)d_in[21];
    const float* ln1b = (const float*)d_in[22];
    const float* ln2g = (const float*)d_in[23];
    const float* ln2b = (const float*)d_in[24];
    const float* wf1  = (const float*)d_in[25];
    const float* bf1  = (const float*)d_in[26];
    const float* wf2  = (const float*)d_in[27];
    const float* bf2  = (const float*)d_in[28];
    const float* bn1g = (const float*)d_in[29];
    const float* bn1b = (const float*)d_in[30];
    const float* fc1w = (const float*)d_in[31];
    const float* fc1b = (const float*)d_in[32];
    const float* bn2g = (const float*)d_in[33];
    const float* bn2b = (const float*)d_in[34];
    const float* fc2w = (const float*)d_in[35];
    const float* fc2b = (const float*)d_in[36];
    float* out = (float*)d_out;

    // ---- workspace layout (bytes), peak ~227 MB ----
    char* wsb = (char*)d_ws;
    short* xb    = (short*)wsb;                        // [N,128] bf16
    short* h1pre = (short*)(wsb + 12800000);           // [N,1024] bf16
    short* h2pre = (short*)(wsb + 12800000);           // [N,512] (h1pre dead)
    short* h3pre = (short*)(wsb + 12800000);           // [N,128] (h2pre dead)
    short* bh1   = (short*)(wsb + 115200000);          // [N,1024] bf16
    short* bh2   = (short*)(wsb + 115200000);          // [N,512] (bh1 dead)
    float* fQ    = (float*)(wsb + 128000000);          // [N,128] fp32 (final state only)
    short* Qb    = (short*)(wsb + 153600000);          // [N,128] bf16 transformer state
    char* tail = wsb + 217600000;
    short* W1p  = (short*)tail;  tail += 262144;       // 128x1024
    short* W2p  = (short*)tail;  tail += 1048576;      // 1024x512
    short* W3p  = (short*)tail;  tail += 131072;       // 512x128
    short* Wvop = (short*)tail;  tail += 196608;       // 6 x 128x128
    short* wf1p = (short*)tail;  tail += 786432;       // 6 x 128x512
    short* wf2p = (short*)tail;  tail += 786432;       // 6 x 512x128
    float* Wvo  = (float*)tail;  tail += 393216;       // 6 x 128x128 fp32
    float* bvo  = (float*)tail;  tail += 3072;         // 6 x 128 fp32
    float* fAS  = (float*)tail;  tail += 1600000;      // [N,8]
    float* fAD  = (float*)tail;  tail += 1600000;      // [N,8]
    float* fDv  = (float*)tail;  tail += 200000;
    float* psum = (float*)tail;  tail += 262144;
    float* pmax = (float*)tail;  tail += 262144;
    float* fHC  = (float*)tail;  tail += 65536;
    int* iDeg   = (int*)tail;    tail += 200000;
    int* iRP    = (int*)tail;    tail += 200004;
    int* iCur   = (int*)tail;    tail += 200000;
    int* iES    = (int*)tail;    tail += 1000000;

    hipMemsetAsync(iDeg, 0, NN * sizeof(int), stream);
    hipMemsetAsync(iCur, 0, NN * sizeof(int), stream);

    count_deg_kernel<<<(ET + 255) / 256, 256, 0, stream>>>(ei, iDeg);
    scan_kernel<<<1, 1024, 0, stream>>>(iDeg, iRP, NN);
    fill_csr_kernel<<<(ET + 255) / 256, 256, 0, stream>>>(ei, iRP, iCur, iES);
    dinv_kernel<<<(NN + 255) / 256, 256, 0, stream>>>(iRP, fDv);

    wvwo_kernel<<<dim3(64, 6), 256, 0, stream>>>(wv, wo, bv, bo, Wvo, bvo);
    auto bprep = [&](const float* B, short* Bp, int K, int N, int ldb, long sStride, int layers) {
        int total = (K >> 5) * (N >> 4) * 64;
        dim3 grid((total + 255) / 256, layers);
        bprep_kernel<<<grid, 256, 0, stream>>>(B, Bp, K, N, ldb, sStride);
    };
    bprep(W1, W1p, 128, 1024, 1024, 0, 1);
    bprep(W2, W2p, 1024, 512, 512, 0, 1);
    bprep(W3, W3p, 512, 128, 128, 0, 1);
    bprep(Wvo, Wvop, 128, 128, 128, 16384, 6);
    bprep(wf1, wf1p, 128, 512, 512, 65536, 6);
    bprep(wf2, wf2p, 512, 128, 128, 65536, 6);
    cast_bf16_kernel<<<(NN * 128 / 4 + 255) / 256, 256, 0, stream>>>(x, xb, NN * 128 / 4);

    const int MB64  = (NN + 63) / 64;                      // 782
    const int MB64p = ((MB64 + 7) / 8) * 8;                // 784

    // ---- GAT layer 1 (K=128, 8 column tiles, LDS-B) ----
    gemm_bf16_kernel<2, false, true, 8, 4><<<MB64p * 8, 256, 0, stream>>>(
        xb, W1p, nullptr, h1pre, as1, ad1, fAS, fAD, 8,
        nullptr, nullptr, nullptr, nullptr, nullptr, NN, 128, 1024);
    gat_agg_fused_kernel<8><<<(NN + 1) / 2, 256, 0, stream>>>(
        (const ushortT*)h1pre, fAS, fAD, b1, iRP, iES, (__hip_bfloat16*)bh1, NN);
    // ---- GAT layer 2 (K=1024, 4 column tiles, LDS-B dbuf) ----
    gemm_bf16_kernel<2, false, true, 4, 0><<<MB64p * 4, 256, 0, stream>>>(
        bh1, W2p, nullptr, h2pre, as2, ad2, fAS, fAD, 4,
        nullptr, nullptr, nullptr, nullptr, nullptr, NN, 1024, 512);
    gat_agg_fused_kernel<4><<<(NN + 1) / 2, 256, 0, stream>>>(
        (const ushortT*)h2pre, fAS, fAD, b2, iRP, iES, (__hip_bfloat16*)bh2, NN);
    // ---- GCN ----
    gemm_bf16_kernel<0, false, true, 1, 0><<<MB64p, 256, 0, stream>>>(
        bh2, W3p, nullptr, h3pre, nullptr, nullptr, nullptr, nullptr, 0,
        nullptr, nullptr, nullptr, nullptr, nullptr, NN, 512, 128);
    gcn_agg_kernel<<<(NN + 1) / 2, 256, 0, stream>>>(
        (const ushortT*)h3pre, fDv, b3, iRP, iES, (__hip_bfloat16*)Qb, NN);
    // ---- Transformer: Wvo gemm + fused FFN per layer ----
    for (int l = 0; l < LL; l++) {
        gemm_bf16_kernel<3, true, false, 1, 4><<<MB64p, 256, 0, stream>>>(
            Qb, Wvop + l * 16384, bvo + l * 128, nullptr, nullptr, nullptr, nullptr, nullptr, 0,
            (const ushortT*)Qb, ln1g + l * 128, ln1b + l * 128, nullptr, (__hip_bfloat16*)Qb,
            NN, 128, 128);
        ffn_fused_kernel<<<MB64, 256, 0, stream>>>(
            Qb, wf1p + l * 65536, bf1 + l * 512, wf2p + l * 65536, bf2 + l * 128,
            ln2g + l * 128, ln2b + l * 128, (l == LL - 1) ? fQ : nullptr, NN);
    }
    // ---- pool + head ----
    pool1_kernel<<<dim3(GG, 8), 128, 0, stream>>>(fQ, batch, psum, pmax, NN);
    pool2_kernel<<<GG, 128, 0, stream>>>(psum, pmax, batch, bn1g, bn1b, fHC, NN);
    head_kernel<<<GG, 64, 0, stream>>>(fHC, fc1w, fc1b, bn2g, bn2b, fc2w, fc2b, out);
}